// Round 1
// 462.811 us; speedup vs baseline: 1.1303x; 1.1303x over previous
//
#include <hip/hip_runtime.h>
#include <hip/hip_bf16.h>

// SAGEMean3: h = [x | mean_in | mean_out] (50000 x 384), out = relu(h @ W + b)
// R5:
//  - prep kernel fuses Wt-transpose (LDS 32x32 tile, coalesced both sides),
//    x->bf16 convert (x8 vectorized), and degree atomics into one launch.
//  - aggregate: one wave per (node, direction) -> 2x wave parallelism.
//  - GEMM: bijective XCD swizzle (grid 3128 = 8*391), u-innermost epilogue so
//    128B-line halves are written back-to-back, nontemporal out stores to keep
//    h/Wt panels resident in L2.

typedef __attribute__((ext_vector_type(8))) short bf16x8;
typedef __attribute__((ext_vector_type(4))) short bf16x4;
typedef __attribute__((ext_vector_type(4))) float f32x4;

#define IN_DIM 128
#define K3 384
#define ODIM 1024

static __device__ inline short bfs(float f) {
    union { __hip_bfloat16 b; short s; } u;
    u.b = __float2bfloat16(f);
    return u.s;
}

// fused: [0, wtB) Wt transpose | [wtB, wtB+convB) x->bf16 | rest: degree atomics
__global__ __launch_bounds__(256) void sage_prep(
    const float* __restrict__ x, const int* __restrict__ src,
    const int* __restrict__ dst, const float* __restrict__ W,
    __hip_bfloat16* __restrict__ xb, __hip_bfloat16* __restrict__ h,
    __hip_bfloat16* __restrict__ Wt, int* __restrict__ deg,
    int n_nodes, int n_edges, int wtB, int convB)
{
    int b = blockIdx.x;
    int t = threadIdx.x;
    if (b < wtB) {
        // Wt[nn][k] = bf16(W[k][nn]); 32x32 tile through LDS
        __shared__ __hip_bfloat16 lds[32][36];
        int tk = b / 32, tn = b % 32;          // 12 x 32 tiles
        int k0 = tk * 32, n0 = tn * 32;
        int r = t >> 3, c = (t & 7) * 4;
        f32x4 w = *(const f32x4*)(W + (size_t)(k0 + r) * ODIM + n0 + c);
#pragma unroll
        for (int i = 0; i < 4; ++i) lds[c + i][r] = __float2bfloat16(w[i]);
        __syncthreads();
        *(bf16x4*)&Wt[(size_t)(n0 + r) * K3 + k0 + c] = *(bf16x4*)&lds[r][c];
        return;
    }
    b -= wtB;
    if (b < convB) {
        int tid = b * 256 + t;                  // over n_nodes*16 (8 elems each)
        if (tid >= n_nodes * 16) return;
        int i = tid >> 4, d8 = (tid & 15) << 3;
        const float* xp = x + (size_t)i * IN_DIM + d8;
        f32x4 a = *(const f32x4*)xp;
        f32x4 c4 = *(const f32x4*)(xp + 4);
        bf16x8 v;
        v[0] = bfs(a.x); v[1] = bfs(a.y); v[2] = bfs(a.z); v[3] = bfs(a.w);
        v[4] = bfs(c4.x); v[5] = bfs(c4.y); v[6] = bfs(c4.z); v[7] = bfs(c4.w);
        *(bf16x8*)(xb + (size_t)i * IN_DIM + d8) = v;
        *(bf16x8*)(h + (size_t)i * K3 + d8) = v;
        return;
    }
    b -= convB;
    int e = b * 256 + t;
    if (e >= n_edges) return;
    atomicAdd(deg + dst[e], 1);            // in-degree of dst
    atomicAdd(deg + n_nodes + src[e], 1);  // out-degree of src
}

// block-level exclusive scan: 1024 elements per 256-thread block
__global__ __launch_bounds__(256) void scan_partial(
    const int* __restrict__ deg, int* __restrict__ off, int* __restrict__ bsum, int n)
{
    __shared__ int s[256];
    int t = threadIdx.x;
    int base = blockIdx.x * 1024 + t * 4;
    int4 v = {0, 0, 0, 0};
    if (base + 3 < n) v = *(const int4*)(deg + base);
    else {
        if (base     < n) v.x = deg[base];
        if (base + 1 < n) v.y = deg[base + 1];
        if (base + 2 < n) v.z = deg[base + 2];
        if (base + 3 < n) v.w = deg[base + 3];
    }
    int tsum = v.x + v.y + v.z + v.w;
    s[t] = tsum;
    __syncthreads();
#pragma unroll
    for (int d = 1; d < 256; d <<= 1) {
        int add = (t >= d) ? s[t - d] : 0;
        __syncthreads();
        s[t] += add;
        __syncthreads();
    }
    int excl = s[t] - tsum;
    if (t == 255) bsum[blockIdx.x] = s[255];
    int e0 = excl, e1 = e0 + v.x, e2 = e1 + v.y, e3 = e2 + v.z;
    if (base     < n) off[base]     = e0;
    if (base + 1 < n) off[base + 1] = e1;
    if (base + 2 < n) off[base + 2] = e2;
    if (base + 3 < n) off[base + 3] = e3;
}

__global__ __launch_bounds__(256) void scan_bsum(int* __restrict__ bsum, int nblk)
{
    __shared__ int s[256];
    int t = threadIdx.x;
    int v = (t < nblk) ? bsum[t] : 0;
    s[t] = v;
    __syncthreads();
#pragma unroll
    for (int d = 1; d < 256; d <<= 1) {
        int add = (t >= d) ? s[t - d] : 0;
        __syncthreads();
        s[t] += add;
        __syncthreads();
    }
    if (t < nblk) bsum[t] = s[t] - v;   // exclusive
}

// add block offset; also initialize cursor = off (for fill)
__global__ __launch_bounds__(256) void scan_add(
    int* __restrict__ off, int* __restrict__ cursor,
    const int* __restrict__ bsum, int n)
{
    int base = blockIdx.x * 1024 + threadIdx.x * 4;
    int b = bsum[blockIdx.x];
#pragma unroll
    for (int j = 0; j < 4; ++j)
        if (base + j < n) {
            int v = off[base + j] + b;
            off[base + j]    = v;
            cursor[base + j] = v;
        }
}

__global__ __launch_bounds__(256) void sage_fill(
    const int* __restrict__ src, const int* __restrict__ dst,
    int* __restrict__ cursor, int* __restrict__ csr, int n_nodes, int n_edges)
{
    int t = blockIdx.x * 256 + threadIdx.x;
    if (t >= n_edges) return;
    int s = src[t];
    int d = dst[t];
    int p0 = atomicAdd(cursor + d, 1);
    csr[p0] = s;                         // in-neighbor of d
    int p1 = atomicAdd(cursor + n_nodes + s, 1);
    csr[p1] = d;                         // out-neighbor of s
}

// one wave per (node, direction): bf16 gathers, fp32 accumulate
__global__ __launch_bounds__(256) void sage_aggregate(
    const __hip_bfloat16* __restrict__ xb, const int* __restrict__ csr,
    const int* __restrict__ off, const int* __restrict__ deg,
    __hip_bfloat16* __restrict__ h, int n_nodes)
{
    int wid  = (int)((blockIdx.x * 256 + threadIdx.x) >> 6);
    int lane = threadIdx.x & 63;
    if (wid >= 2 * n_nodes) return;
    int i = wid >> 1;
    int d = wid & 1;
    int idx = i + d * n_nodes;

    float2 a = {0.f, 0.f};
    int b0 = off[idx], dg = deg[idx];

#define GATHER(nb) { \
    __hip_bfloat162 v = ((const __hip_bfloat162*)(xb + (size_t)(nb) * IN_DIM))[lane]; \
    a.x += __low2float(v); a.y += __high2float(v); }

    int e = 0;
    for (; e + 3 < dg; e += 4) {
        int a0 = csr[b0 + e], a1 = csr[b0 + e + 1], a2 = csr[b0 + e + 2], a3 = csr[b0 + e + 3];
        GATHER(a0) GATHER(a1) GATHER(a2) GATHER(a3)
    }
    for (; e < dg; ++e) { int a0 = csr[b0 + e]; GATHER(a0) }
#undef GATHER

    float inv = 1.0f / (float)max(dg, 1);
    __hip_bfloat162 p;
    p.x = __float2bfloat16(a.x * inv);
    p.y = __float2bfloat16(a.y * inv);
    ((__hip_bfloat162*)(h + (size_t)i * K3))[64 + (d << 6) + lane] = p;
}

// 128x128 block tile, 2x2 waves of 64x64, BK=32, double-buffered LDS staging.
// Stage geometry per op per ktile: 128 rows x 4 ksegs(16B) = 512 chunks,
// 2 rounds x 256 threads. LDS slot seg of row r holds global kseg seg^(r&3).
__global__ __launch_bounds__(256, 4) void sage_gemm(
    const __hip_bfloat16* __restrict__ h, const __hip_bfloat16* __restrict__ Wt,
    const float* __restrict__ bias, float* __restrict__ out, int n_nodes)
{
    __shared__ __hip_bfloat16 Asm[2][128 * 32];   // 2 x 8 KB
    __shared__ __hip_bfloat16 Bsm[2][128 * 32];   // 2 x 8 KB

    int t    = threadIdx.x;
    int wave = t >> 6;
    int lane = t & 63;

    // bijective XCD swizzle: same-tm blocks land on one XCD's L2 (grid % 8 == 0)
    int bid = blockIdx.x;
    int sid = bid;
    if ((gridDim.x & 7) == 0) {
        int cpx = gridDim.x >> 3;
        sid = (bid & 7) * cpx + (bid >> 3);
    }
    int tn   = sid & 7;       // 8 n-tiles of 128
    int tm   = sid >> 3;      // m-tiles of 128
    int m0   = tm * 128;
    int n0   = tn * 128;
    int wm   = wave >> 1;
    int wn   = wave & 1;
    int m    = lane & 15;
    int quad = lane >> 4;

    // per-thread staging addresses: chunks t and t+256 (rows r, r+64; same seg)
    int srow = t >> 2;
    int seg  = t & 3;
    int g    = seg ^ (srow & 3);     // (srow+64)&3 == srow&3
    int ga0  = m0 + srow;       if (ga0 >= n_nodes) ga0 = n_nodes - 1;
    int ga1  = m0 + srow + 64;  if (ga1 >= n_nodes) ga1 = n_nodes - 1;
    const __hip_bfloat16* gA0 = h  + (size_t)ga0 * K3 + g * 8;
    const __hip_bfloat16* gA1 = h  + (size_t)ga1 * K3 + g * 8;
    const __hip_bfloat16* gB0 = Wt + (size_t)(n0 + srow) * K3 + g * 8;
    const __hip_bfloat16* gB1 = Wt + (size_t)(n0 + srow + 64) * K3 + g * 8;
    // wave-uniform LDS bases (+ lane*16 implicit)
    int l0 = (0 * 256 + wave * 64) * 8;
    int l1 = (1 * 256 + wave * 64) * 8;

    f32x4 acc[4][4];
#pragma unroll
    for (int s = 0; s < 4; ++s)
#pragma unroll
        for (int u = 0; u < 4; ++u) acc[s][u] = (f32x4){0.f, 0.f, 0.f, 0.f};

    // prologue: stage ktile 0 into buffer 0
    __builtin_amdgcn_global_load_lds(gA0, &Asm[0][l0], 16, 0, 0);
    __builtin_amdgcn_global_load_lds(gA1, &Asm[0][l1], 16, 0, 0);
    __builtin_amdgcn_global_load_lds(gB0, &Bsm[0][l0], 16, 0, 0);
    __builtin_amdgcn_global_load_lds(gB1, &Bsm[0][l1], 16, 0, 0);

    int slot = quad ^ (m & 3);
#pragma unroll
    for (int kt = 0; kt < 12; ++kt) {
        int p = kt & 1;
        __syncthreads();   // drains stage(kt) [in flight for one full compute] + prior reads
        if (kt < 11) {     // stage kt+1 into the other buffer, overlapped with compute
            int koff = (kt + 1) * 32;
            __builtin_amdgcn_global_load_lds(gA0 + koff, &Asm[p ^ 1][l0], 16, 0, 0);
            __builtin_amdgcn_global_load_lds(gA1 + koff, &Asm[p ^ 1][l1], 16, 0, 0);
            __builtin_amdgcn_global_load_lds(gB0 + koff, &Bsm[p ^ 1][l0], 16, 0, 0);
            __builtin_amdgcn_global_load_lds(gB1 + koff, &Bsm[p ^ 1][l1], 16, 0, 0);
        }
        bf16x8 a[4], b[4];
#pragma unroll
        for (int s = 0; s < 4; ++s) {
            int row = wm * 64 + s * 16 + m;
            a[s] = *(const bf16x8*)&Asm[p][row * 32 + slot * 8];
        }
#pragma unroll
        for (int u = 0; u < 4; ++u) {
            int row = wn * 64 + u * 16 + m;
            b[u] = *(const bf16x8*)&Bsm[p][row * 32 + slot * 8];
        }
#pragma unroll
        for (int s = 0; s < 4; ++s)
#pragma unroll
            for (int u = 0; u < 4; ++u)
                acc[s][u] = __builtin_amdgcn_mfma_f32_16x16x32_bf16(a[s], b[u], acc[s][u], 0, 0, 0);
    }

    // epilogue: u innermost so the two 64B halves of each 128B line are written
    // back-to-back; nontemporal so the 205MB out stream doesn't evict h/Wt in L2.
    float bv[4];
#pragma unroll
    for (int u = 0; u < 4; ++u) bv[u] = bias[n0 + wn * 64 + u * 16 + m];

    bool full = (m0 + 128 <= n_nodes);   // uniform per block
    if (full) {
#pragma unroll
        for (int s = 0; s < 4; ++s) {
            int r0 = m0 + wm * 64 + s * 16 + quad * 4;
#pragma unroll
            for (int r = 0; r < 4; ++r) {
                float* orow = out + (size_t)(r0 + r) * ODIM + n0 + wn * 64 + m;
#pragma unroll
                for (int u = 0; u < 4; ++u)
                    __builtin_nontemporal_store(fmaxf(acc[s][u][r] + bv[u], 0.f), orow + u * 16);
            }
        }
    } else {
#pragma unroll
        for (int s = 0; s < 4; ++s) {
            int r0 = m0 + wm * 64 + s * 16 + quad * 4;
#pragma unroll
            for (int r = 0; r < 4; ++r) {
                if (r0 + r >= n_nodes) continue;
                float* orow = out + (size_t)(r0 + r) * ODIM + n0 + wn * 64 + m;
#pragma unroll
                for (int u = 0; u < 4; ++u)
                    __builtin_nontemporal_store(fmaxf(acc[s][u][r] + bv[u], 0.f), orow + u * 16);
            }
        }
    }
}

extern "C" void kernel_launch(void* const* d_in, const int* in_sizes, int n_in,
                              void* d_out, int out_size, void* d_ws, size_t ws_size,
                              hipStream_t stream)
{
    const float* x    = (const float*)d_in[0];
    const int*   ei   = (const int*)d_in[1];
    const float* W    = (const float*)d_in[2];
    const float* bias = (const float*)d_in[3];

    int n_nodes = in_sizes[0] / IN_DIM;
    int n_edges = in_sizes[1] / 2;
    const int* src = ei;
    const int* dst = ei + n_edges;
    int n2 = 2 * n_nodes;

    // ws layout: deg[2N] | cursor[2N] | off[2N] | bsum[256] | csr[2E] | h | Wt | xb
    char* ws = (char*)d_ws;
    int* deg    = (int*)ws;
    int* cursor = deg + n2;
    int* off    = cursor + n2;
    int* bsum   = off + n2;
    int* csr    = bsum + 256;
    __hip_bfloat16* h  = (__hip_bfloat16*)(csr + 2 * n_edges);
    __hip_bfloat16* Wt = h  + (size_t)n_nodes * K3;
    __hip_bfloat16* xb = Wt + (size_t)K3 * ODIM;

    hipMemsetAsync(deg, 0, (size_t)n2 * sizeof(int), stream);

    int wtB   = (K3 / 32) * (ODIM / 32);             // 384
    int convB = (n_nodes * 16 + 255) / 256;          // 3125
    int degB  = (n_edges + 255) / 256;               // 2344
    sage_prep<<<wtB + convB + degB, 256, 0, stream>>>(
        x, src, dst, W, xb, h, Wt, deg, n_nodes, n_edges, wtB, convB);

    int nblk = (n2 + 1023) / 1024;   // 98 for N=50000
    scan_partial<<<nblk, 256, 0, stream>>>(deg, off, bsum, n2);
    scan_bsum<<<1, 256, 0, stream>>>(bsum, nblk);
    scan_add<<<nblk, 256, 0, stream>>>(off, cursor, bsum, n2);

    sage_fill<<<degB, 256, 0, stream>>>(src, dst, cursor, csr, n_nodes, n_edges);

    sage_aggregate<<<(n2 + 3) / 4, 256, 0, stream>>>(xb, csr, off, deg, h, n_nodes);

    int tiles_m = (n_nodes + 127) / 128;         // 391
    int blocks  = tiles_m * (ODIM / 128);        // 3128
    sage_gemm<<<blocks, 256, 0, stream>>>(h, Wt, bias, (float*)d_out, n_nodes);
}